// Round 1
// baseline (14801.770 us; speedup 1.0000x reference)
//
#include <hip/hip_runtime.h>
#include <hip/hip_bf16.h>

typedef __hip_bfloat16 bf16;

#define NB 16
#define PLANE (256*256)

static __device__ __forceinline__ float ldf(const float* p){ return *p; }
static __device__ __forceinline__ float ldf(const bf16* p){ return __bfloat162float(*p); }
static __device__ __forceinline__ void stf(float* p, float v){ *p = v; }
static __device__ __forceinline__ void stf(bf16* p, float v){ *p = __float2bfloat16(v); }

// ---------------- conv 3x3 SAME, NCHW, OIHW weights ----------------
// block = 256 threads = 16x16 output tile, grid = (16,16,B)
// LDS: input tile (CIN x 18 x 18, TIN) + weights (CIN*9*COUT fp32, layout [ci*9+k][co])
template<int CIN, int SPLIT, int COUT, bool RELU, typename TIN, typename TOUT>
__global__ __launch_bounds__(256)
void conv3x3(const TIN* __restrict__ in, const TIN* __restrict__ in2,
             const float* __restrict__ wgt, const float* __restrict__ bias,
             TOUT* __restrict__ out)
{
    __shared__ TIN  s_in[CIN][18][18];
    __shared__ float s_w[CIN*9*COUT];
    const int n  = blockIdx.z;
    const int ty0 = blockIdx.y * 16, tx0 = blockIdx.x * 16;
    const int tid = threadIdx.x;

    for (int idx = tid; idx < CIN*9*COUT; idx += 256) {
        int co = idx % COUT; int rest = idx / COUT;   // rest = ci*9 + k
        s_w[idx] = wgt[(co*CIN + rest/9)*9 + rest%9];
    }
    for (int idx = tid; idx < CIN*18*18; idx += 256) {
        int ci = idx / (18*18); int rr = idx % (18*18);
        int yy = rr / 18, xx = rr % 18;
        int y = ty0 + yy - 1, x = tx0 + xx - 1;
        float v = 0.f;
        if (y >= 0 && y < 256 && x >= 0 && x < 256) {
            if (ci < SPLIT) v = ldf(&in [((size_t)(n*SPLIT + ci)*256 + y)*256 + x]);
            else            v = ldf(&in2[((size_t)(n*(CIN-SPLIT) + (ci-SPLIT))*256 + y)*256 + x]);
        }
        stf(&s_in[ci][yy][xx], v);
    }
    __syncthreads();

    const int ty = tid >> 4, tx = tid & 15;
    float acc[COUT];
    #pragma unroll
    for (int co = 0; co < COUT; co++) acc[co] = bias[co];

    for (int ci = 0; ci < CIN; ci++) {
        #pragma unroll
        for (int ky = 0; ky < 3; ky++)
        #pragma unroll
        for (int kx = 0; kx < 3; kx++) {
            float v = ldf(&s_in[ci][ty+ky][tx+kx]);
            const float* wp = &s_w[(ci*9 + ky*3 + kx)*COUT];
            #pragma unroll
            for (int co = 0; co < COUT; co++) acc[co] = fmaf(v, wp[co], acc[co]);
        }
    }
    const int y = ty0 + ty, x = tx0 + tx;
    #pragma unroll
    for (int co = 0; co < COUT; co++) {
        float v = acc[co];
        if (RELU) v = fmaxf(v, 0.f);
        stf(&out[((size_t)(n*COUT + co)*256 + y)*256 + x], v);
    }
}

// ---------------- squared neighbor differences, summed over 32 channels ----------------
// block = 256 (one row), grid = B*256.  dv[n,i,j] = sum_c (f[c,i+1,j]-f[c,i,j])^2 (i<255)
template<bool ACCUM>
__global__ __launch_bounds__(256)
void dvdh_kernel(const bf16* __restrict__ f, float* __restrict__ dv, float* __restrict__ dh)
{
    int bid = blockIdx.x;
    int n = bid >> 8, i = bid & 255, j = threadIdx.x;
    const bf16* base = f + ((size_t)n*32)*PLANE + i*256 + j;
    float adv = 0.f, adh = 0.f;
    #pragma unroll 4
    for (int c = 0; c < 32; c++) {
        const bf16* pc = base + (size_t)c*PLANE;
        float fc = __bfloat162float(pc[0]);
        float fr = (j < 255) ? __bfloat162float(pc[1])   : fc;
        float fd = (i < 255) ? __bfloat162float(pc[256]) : fc;
        adh += (fr-fc)*(fr-fc);
        adv += (fd-fc)*(fd-fc);
    }
    int o = (n*256 + i)*256 + j;
    if (ACCUM) { dv[o] += adv; dh[o] += adh; }
    else       { dv[o]  = adv; dh[o]  = adh; }
}

// ---------------- affinity: 5 planes (w_up,w_dn,w_lf,w_rt,center) ----------------
__global__ __launch_bounds__(256)
void aff_kernel(const float* __restrict__ dv, const float* __restrict__ dh,
                const float* __restrict__ llam, const float* __restrict__ lmu,
                float* __restrict__ aff)
{
    int bid = blockIdx.x;
    int n = bid >> 8, h = bid & 255, w = threadIdx.x;
    float mu = expf(lmu[0]), lam = expf(llam[0]);
    int rb = (n*256 + h)*256 + w;
    float w_up = (h > 0)   ? expf(-mu * dv[rb - 256]) : 0.f;
    float w_dn = (h < 255) ? expf(-mu * dv[rb])       : 0.f;
    float w_lf = (w > 0)   ? expf(-mu * dh[rb - 1])   : 0.f;
    float w_rt = (w < 255) ? expf(-mu * dh[rb])       : 0.f;
    float ctr  = w_up + w_dn + w_lf + w_rt + lam;
    float* a = aff + ((size_t)n*5)*PLANE + h*256 + w;
    a[0]        = w_up;
    a[PLANE]    = w_dn;
    a[2*PLANE]  = w_lf;
    a[3*PLANE]  = w_rt;
    a[4*PLANE]  = ctr;
}

// ---------------- RHS: b = lam * mask * source upsampled / 64 ----------------
__global__ __launch_bounds__(256)
void brhs_kernel(const float* __restrict__ src, const float* __restrict__ mask,
                 const float* __restrict__ llam, float* __restrict__ b)
{
    int gid = blockIdx.x*256 + threadIdx.x;
    int n = gid >> 16, rem = gid & 65535, h = rem >> 8, w = rem & 255;
    float lam = expf(llam[0]);
    int bi = n*1024 + (h>>3)*32 + (w>>3);
    b[gid] = lam * mask[bi] * src[bi] * (1.f/64.f);
}

// ---------------- 8x8 block sums: (B,256,256) -> (B,32,32) ----------------
__global__ __launch_bounds__(64)
void bsum_kernel(const float* __restrict__ v, float* __restrict__ bs)
{
    int bid = blockIdx.x;                  // n*1024 + by*32 + bx
    int n = bid >> 10, by = (bid >> 5) & 31, bx = bid & 31;
    int t = threadIdx.x, dy = t >> 3, dx = t & 7;
    float val = v[((size_t)n*256 + by*8 + dy)*256 + bx*8 + dx];
    #pragma unroll
    for (int o = 32; o > 0; o >>= 1) val += __shfl_down(val, o, 64);
    if (t == 0) bs[bid] = val;
}

__global__ void zero_scal(float* s) { s[threadIdx.x] = 0.f; }

// ---------------- CG machinery ----------------
static __device__ __forceinline__ float cg_stencil(const float* __restrict__ aff,
    const float* __restrict__ y, const float* __restrict__ bs,
    const float* __restrict__ mask, float lam, int n, int h, int w)
{
    const float* a  = aff + ((size_t)n*5)*PLANE + h*256 + w;
    const float* yp = y + (size_t)n*PLANE + h*256 + w;
    float s = 0.f;
    if (h > 0)   s += a[0]       * yp[-256];
    if (h < 255) s += a[PLANE]   * yp[256];
    if (w > 0)   s += a[2*PLANE] * yp[-1];
    if (w < 255) s += a[3*PLANE] * yp[1];
    float deg = a[4*PLANE] - lam;
    int bi = n*1024 + (h>>3)*32 + (w>>3);
    return deg * yp[0] - s + lam * mask[bi] * bs[bi] * (1.f/4096.f);
}

static __device__ __forceinline__ float block_sum(float v)
{
    #pragma unroll
    for (int o = 32; o > 0; o >>= 1) v += __shfl_down(v, o, 64);
    __shared__ float sh[4];
    int wv = threadIdx.x >> 6;
    if ((threadIdx.x & 63) == 0) sh[wv] = v;
    __syncthreads();
    return sh[0] + sh[1] + sh[2] + sh[3];
}

__global__ __launch_bounds__(256)
void cg_init_kernel(const float* __restrict__ aff, const float* __restrict__ ybic,
    const float* __restrict__ bs, const float* __restrict__ mask,
    const float* __restrict__ brhs, const float* __restrict__ llam,
    float* __restrict__ x, float* __restrict__ r, float* __restrict__ p,
    float* __restrict__ gamma0)
{
    int gid = blockIdx.x*256 + threadIdx.x;
    int n = gid >> 16, rem = gid & 65535, h = rem >> 8, w = rem & 255;
    float lam = expf(llam[0]);
    float ax = cg_stencil(aff, ybic, bs, mask, lam, n, h, w);
    float r0 = brhs[gid] - ax;
    r[gid] = r0; p[gid] = r0; x[gid] = ybic[gid];
    float t = block_sum(r0*r0);
    if (threadIdx.x == 0) atomicAdd(gamma0, t);
}

__global__ __launch_bounds__(256)
void cg_matvec_kernel(const float* __restrict__ aff, const float* __restrict__ p,
    const float* __restrict__ bs, const float* __restrict__ mask,
    const float* __restrict__ llam, float* __restrict__ Ap, float* __restrict__ pAp)
{
    int gid = blockIdx.x*256 + threadIdx.x;
    int n = gid >> 16, rem = gid & 65535, h = rem >> 8, w = rem & 255;
    float lam = expf(llam[0]);
    float ap = cg_stencil(aff, p, bs, mask, lam, n, h, w);
    Ap[gid] = ap;
    float t = block_sum(p[gid] * ap);
    if (threadIdx.x == 0) atomicAdd(pAp, t);
}

__global__ __launch_bounds__(256)
void cg_update_kernel(float* __restrict__ x, float* __restrict__ r,
    const float* __restrict__ p, const float* __restrict__ Ap,
    const float* __restrict__ gk, const float* __restrict__ pApk,
    float* __restrict__ gk1)
{
    int gid = blockIdx.x*256 + threadIdx.x;
    float alpha = *gk / *pApk;
    x[gid] += alpha * p[gid];
    float rn = r[gid] - alpha * Ap[gid];
    r[gid] = rn;
    float t = block_sum(rn*rn);
    if (threadIdx.x == 0) atomicAdd(gk1, t);
}

__global__ __launch_bounds__(256)
void cg_pupdate_kernel(float* __restrict__ p, const float* __restrict__ r,
    const float* __restrict__ gk1, const float* __restrict__ gk)
{
    int gid = blockIdx.x*256 + threadIdx.x;
    float beta = *gk1 / *gk;
    p[gid] = r[gid] + beta * p[gid];
}

// ---------------- host ----------------
extern "C" void kernel_launch(void* const* d_in, const int* in_sizes, int n_in,
                              void* d_out, int out_size, void* d_ws, size_t ws_size,
                              hipStream_t stream)
{
    (void)in_sizes; (void)n_in; (void)out_size; (void)ws_size;
    const float* guide = (const float*)d_in[0];
    const float* source= (const float*)d_in[1];
    const float* mask  = (const float*)d_in[2];
    const float* ybic  = (const float*)d_in[3];
    const float* gw1 = (const float*)d_in[4];  const float* gb1 = (const float*)d_in[5];
    const float* gw2 = (const float*)d_in[6];  const float* gb2 = (const float*)d_in[7];
    const float* sw1 = (const float*)d_in[8];  const float* sb1 = (const float*)d_in[9];
    const float* sw2 = (const float*)d_in[10]; const float* sb2 = (const float*)d_in[11];
    const float* vw1 = (const float*)d_in[12]; const float* vb1 = (const float*)d_in[13];
    const float* vw2 = (const float*)d_in[14]; const float* vb2 = (const float*)d_in[15];
    const float* vw3 = (const float*)d_in[16]; const float* vb3 = (const float*)d_in[17];
    const float* llam = (const float*)d_in[18];
    const float* lmu  = (const float*)d_in[19];

    float* out     = (float*)d_out;
    float* x_out   = out;                 // y_pred (16,1,256,256)
    float* var_out = out + 1048576;       // var
    float* aff_out = out + 2097152;       // aff (16,5,256,256)

    char* ws = (char*)d_ws;
    size_t o = 0;
    bf16* bufA = (bf16*)(ws + o); o += (size_t)NB*32*PLANE*2;
    bf16* bufB = (bf16*)(ws + o); o += (size_t)NB*32*PLANE*2;
    float* dv  = (float*)(ws + o); o += (size_t)NB*PLANE*4;
    float* dh  = (float*)(ws + o); o += (size_t)NB*PLANE*4;
    float* rr  = (float*)(ws + o); o += (size_t)NB*PLANE*4;
    float* pp  = (float*)(ws + o); o += (size_t)NB*PLANE*4;
    float* Ap  = (float*)(ws + o); o += (size_t)NB*PLANE*4;
    float* brhs= (float*)(ws + o); o += (size_t)NB*PLANE*4;
    float* bs  = (float*)(ws + o); o += 16384*4;
    float* scal= (float*)(ws + o); o += 1024;
    float* gamma = scal;          // [0..100]
    float* pAp   = scal + 112;    // [0..99]

    dim3 cgrid(16, 16, NB);

    // feature branch g = conv(relu(conv(guide)))
    conv3x3<3,3,32,true ,float,bf16><<<cgrid,256,0,stream>>>(guide, guide, gw1, gb1, bufA);
    conv3x3<32,32,32,false,bf16,bf16><<<cgrid,256,0,stream>>>(bufA, bufA, gw2, gb2, bufB);
    dvdh_kernel<false><<<4096,256,0,stream>>>(bufB, dv, dh);
    // feature branch s = conv(relu(conv(y_bicubic)))
    conv3x3<1,1,32,true ,float,bf16><<<cgrid,256,0,stream>>>(ybic, ybic, sw1, sb1, bufA);
    conv3x3<32,32,32,false,bf16,bf16><<<cgrid,256,0,stream>>>(bufA, bufA, sw2, sb2, bufB);
    dvdh_kernel<true><<<4096,256,0,stream>>>(bufB, dv, dh);
    aff_kernel<<<4096,256,0,stream>>>(dv, dh, llam, lmu, aff_out);
    // variance branch
    conv3x3<4,3,32,true ,float,bf16><<<cgrid,256,0,stream>>>(guide, ybic, vw1, vb1, bufA);
    conv3x3<32,32,32,true ,bf16,bf16><<<cgrid,256,0,stream>>>(bufA, bufA, vw2, vb2, bufB);
    conv3x3<32,32,1,false,bf16,float><<<cgrid,256,0,stream>>>(bufB, bufB, vw3, vb3, var_out);
    // CG setup
    zero_scal<<<1,256,0,stream>>>(scal);
    brhs_kernel<<<4096,256,0,stream>>>(source, mask, llam, brhs);
    bsum_kernel<<<16384,64,0,stream>>>(ybic, bs);
    cg_init_kernel<<<4096,256,0,stream>>>(aff_out, ybic, bs, mask, brhs, llam,
                                          x_out, rr, pp, gamma);
    // 100 CG iterations (fixed; system is far from tol=1e-6 at iter 100)
    for (int k = 0; k < 100; k++) {
        bsum_kernel<<<16384,64,0,stream>>>(pp, bs);
        cg_matvec_kernel<<<4096,256,0,stream>>>(aff_out, pp, bs, mask, llam, Ap, pAp + k);
        cg_update_kernel<<<4096,256,0,stream>>>(x_out, rr, pp, Ap, gamma + k, pAp + k, gamma + k + 1);
        cg_pupdate_kernel<<<4096,256,0,stream>>>(pp, rr, gamma + k + 1, gamma + k);
    }
}